// Round 1
// baseline (77562.543 us; speedup 1.0000x reference)
//
#include <hip/hip_runtime.h>
#include <hip/hip_bf16.h>

#define EMB 512
#define HIDDEN 512
#define BATCH 32
#define SEQ 2048
#define NSLICE 128   // WGs per layer
#define JPW 4        // hidden columns per WG (512/128)
#define ROWS 16      // 4 gates * JPW
#define NTHREADS 256

__device__ __forceinline__ float sigf(float x) { return 1.0f / (1.0f + __expf(-x)); }
__device__ __forceinline__ float tanh_fast(float x) { return 2.0f * sigf(2.0f * x) - 1.0f; }

// One launch per pipeline phase k:
//   WGs [0,128):   layer 0, step t = k      (if t < SEQ)
//   WGs [128,256): layer 1, step t = k - 1  (if t >= 0)
// h buffers double-buffered by step parity; c updated in place (exclusive owner).
// h layout transposed: h[j][b]  (j-major, 32 floats per row) for coalesced reads.
__global__ __launch_bounds__(NTHREADS) void lstm_step(
    int k,
    const int* __restrict__ tokens,
    const float* __restrict__ emb,
    const float* __restrict__ w_ih,
    const float* __restrict__ w_hh,
    const float* __restrict__ b_ih,
    const float* __restrict__ b_hh,
    float* __restrict__ h0a, float* __restrict__ h0b,
    float* __restrict__ h1a, float* __restrict__ h1b,
    float* __restrict__ cs0, float* __restrict__ cs1)
{
    __shared__ __hip_bfloat16 xT[EMB][BATCH + 1];  // layer-0 input, transposed (+1 pad: bank spread)
    __shared__ float gbuf[ROWS][BATCH];
    __shared__ int tok[BATCH];

    const int wg  = blockIdx.x;
    const int tid = threadIdx.x;
    const bool l1 = (wg >= NSLICE);
    const int s   = l1 ? (wg - NSLICE) : wg;
    const int t   = l1 ? (k - 1) : k;
    if (t < 0 || t >= SEQ) return;      // uniform per-WG
    const int layer = l1 ? 1 : 0;

    // buffer selection by step parity
    const float* hsrc;          // recurrent input  h[t-1]
    float* hout;                // output           h[t]
    const float* esrc = nullptr;// layer-1 "x" input = h0[t]
    float* cst = l1 ? cs1 : cs0;
    if (!l1) {
        hout = (t & 1) ? h0b : h0a;
        hsrc = (t & 1) ? h0a : h0b;
    } else {
        hout = (t & 1) ? h1b : h1a;
        hsrc = (t & 1) ? h1a : h1b;
        esrc = (t & 1) ? h0b : h0a;   // layer-0 output at the same step t
    }

    if (!l1) {
        // stage x_t transposed into LDS as bf16
        if (tid < BATCH) tok[tid] = tokens[tid * SEQ + t];
        __syncthreads();
        for (int i = tid; i < EMB * BATCH; i += NTHREADS) {
            int b = i >> 9;            // i / EMB
            int e = i & (EMB - 1);
            xT[e][b] = __float2bfloat16(emb[(size_t)tok[b] * EMB + e]);
        }
    }
    __syncthreads();

    // dot-product phase: thread -> (row rr, batch pair bp)
    const int rr   = tid >> 4;        // 0..15
    const int bp   = tid & 15;        // batch b = bp and bp+16
    const int gate = rr >> 2;
    const int jj   = rr & 3;
    const int row  = gate * HIDDEN + s * JPW + jj;   // gate row in [0, 2048)
    const float* wih = w_ih + ((size_t)layer * 4 * HIDDEN + row) * EMB;
    const float* whh = w_hh + ((size_t)layer * 4 * HIDDEN + row) * HIDDEN;

    float a0 = 0.f, a1 = 0.f, a2 = 0.f, a3 = 0.f;   // b = bp
    float d0 = 0.f, d1 = 0.f, d2 = 0.f, d3 = 0.f;   // b = bp+16

    if (!l1) {
        #pragma unroll 2
        for (int e = 0; e < EMB; e += 4) {
            const float4 w4 = *(const float4*)(wih + e);
            a0 += w4.x * __bfloat162float(xT[e + 0][bp]);
            a1 += w4.y * __bfloat162float(xT[e + 1][bp]);
            a2 += w4.z * __bfloat162float(xT[e + 2][bp]);
            a3 += w4.w * __bfloat162float(xT[e + 3][bp]);
            d0 += w4.x * __bfloat162float(xT[e + 0][bp + 16]);
            d1 += w4.y * __bfloat162float(xT[e + 1][bp + 16]);
            d2 += w4.z * __bfloat162float(xT[e + 2][bp + 16]);
            d3 += w4.w * __bfloat162float(xT[e + 3][bp + 16]);
        }
    } else {
        #pragma unroll 2
        for (int e = 0; e < EMB; e += 4) {
            const float4 w4 = *(const float4*)(wih + e);
            a0 += w4.x * esrc[(e + 0) * BATCH + bp];
            a1 += w4.y * esrc[(e + 1) * BATCH + bp];
            a2 += w4.z * esrc[(e + 2) * BATCH + bp];
            a3 += w4.w * esrc[(e + 3) * BATCH + bp];
            d0 += w4.x * esrc[(e + 0) * BATCH + bp + 16];
            d1 += w4.y * esrc[(e + 1) * BATCH + bp + 16];
            d2 += w4.z * esrc[(e + 2) * BATCH + bp + 16];
            d3 += w4.w * esrc[(e + 3) * BATCH + bp + 16];
        }
    }

    #pragma unroll 2
    for (int j = 0; j < HIDDEN; j += 4) {
        const float4 w4 = *(const float4*)(whh + j);
        a0 += w4.x * hsrc[(j + 0) * BATCH + bp];
        a1 += w4.y * hsrc[(j + 1) * BATCH + bp];
        a2 += w4.z * hsrc[(j + 2) * BATCH + bp];
        a3 += w4.w * hsrc[(j + 3) * BATCH + bp];
        d0 += w4.x * hsrc[(j + 0) * BATCH + bp + 16];
        d1 += w4.y * hsrc[(j + 1) * BATCH + bp + 16];
        d2 += w4.z * hsrc[(j + 2) * BATCH + bp + 16];
        d3 += w4.w * hsrc[(j + 3) * BATCH + bp + 16];
    }

    const float bias = b_ih[layer * 4 * HIDDEN + row] + b_hh[layer * 4 * HIDDEN + row];
    gbuf[rr][bp]      = (a0 + a1) + (a2 + a3) + bias;
    gbuf[rr][bp + 16] = (d0 + d1) + (d2 + d3) + bias;
    __syncthreads();

    // elementwise cell update: 128 threads, each owns (jj2, b)
    if (tid < 4 * BATCH) {
        const int jj2 = tid >> 5;     // 0..3
        const int b   = tid & 31;
        const float gi = gbuf[0 * 4 + jj2][b];
        const float gf = gbuf[1 * 4 + jj2][b];
        const float gg = gbuf[2 * 4 + jj2][b];
        const float go = gbuf[3 * 4 + jj2][b];
        const int idx = (s * JPW + jj2) * BATCH + b;
        const float cc = sigf(gf) * cst[idx] + sigf(gi) * tanh_fast(gg);
        cst[idx] = cc;
        hout[idx] = sigf(go) * tanh_fast(cc);
    }
}

__global__ void fc_kernel(const float* __restrict__ h1fin,
                          const float* __restrict__ fc_w,
                          const float* __restrict__ fc_b,
                          float* __restrict__ out)
{
    const int tid = threadIdx.x;
    if (tid >= BATCH * 2) return;
    const int b = tid >> 1;
    const int o = tid & 1;
    float acc = 0.f;
    for (int j = 0; j < HIDDEN; ++j)
        acc += h1fin[j * BATCH + b] * fc_w[o * HIDDEN + j];
    out[b * 2 + o] = sigf(acc + fc_b[o]);
}

extern "C" void kernel_launch(void* const* d_in, const int* in_sizes, int n_in,
                              void* d_out, int out_size, void* d_ws, size_t ws_size,
                              hipStream_t stream)
{
    const int*   tokens = (const int*)d_in[0];
    const float* emb    = (const float*)d_in[1];
    const float* w_ih   = (const float*)d_in[2];
    const float* w_hh   = (const float*)d_in[3];
    const float* b_ih   = (const float*)d_in[4];
    const float* b_hh   = (const float*)d_in[5];
    const float* fc_w   = (const float*)d_in[6];
    const float* fc_b   = (const float*)d_in[7];

    float* ws = (float*)d_ws;
    const int S = HIDDEN * BATCH;           // 16384 floats
    float* h0a = ws + 0 * S;
    float* h0b = ws + 1 * S;
    float* h1a = ws + 2 * S;
    float* h1b = ws + 3 * S;
    float* cs0 = ws + 4 * S;
    float* cs1 = ws + 5 * S;

    // zero state (t = -1 inputs read the parity-1 buffers; c in place)
    hipMemsetAsync(d_ws, 0, (size_t)6 * S * sizeof(float), stream);

    for (int k = 0; k <= SEQ; ++k) {
        lstm_step<<<dim3(2 * NSLICE), dim3(NTHREADS), 0, stream>>>(
            k, tokens, emb, w_ih, w_hh, b_ih, b_hh,
            h0a, h0b, h1a, h1b, cs0, cs1);
    }
    // last layer-1 write was step t=2047 -> parity 1 -> h1b
    fc_kernel<<<dim3(1), dim3(64), 0, stream>>>(h1b, fc_w, fc_b, (float*)d_out);
}

// Round 2
// 44403.934 us; speedup vs baseline: 1.7467x; 1.7467x over previous
//
#include <hip/hip_runtime.h>

#define SEQ   2048
#define EMBD  512
#define HID   512
#define NB    32      // batch
#define NSL   128     // WG slices per layer (each owns 4 hidden cols x 4 gates = 16 gate rows)
#define NWG   256
#define NTHR  256

typedef __attribute__((ext_vector_type(8))) short bf16x8;
typedef __attribute__((ext_vector_type(4))) float f32x4;

__device__ __forceinline__ float sigf(float x) { return 1.0f / (1.0f + __expf(-x)); }
__device__ __forceinline__ float tanhf_fast(float x) {
    float e = __expf(2.0f * x);
    return (e - 1.0f) / (e + 1.0f);
}
// RNE f32 -> bf16 (bit trick; values here are tame, no NaN handling needed)
__device__ __forceinline__ short f2bf(float f) {
    unsigned u = __float_as_uint(f);
    unsigned r = (u + 0x7FFFu + ((u >> 16) & 1u)) >> 16;
    return (short)r;
}
__device__ __forceinline__ float bf2f(unsigned short s) {
    return __uint_as_float(((unsigned)s) << 16);
}
__device__ __forceinline__ bf16x8 cvt8(float4 a, float4 b) {
    bf16x8 r;
    r[0] = f2bf(a.x); r[1] = f2bf(a.y); r[2] = f2bf(a.z); r[3] = f2bf(a.w);
    r[4] = f2bf(b.x); r[5] = f2bf(b.y); r[6] = f2bf(b.z); r[7] = f2bf(b.w);
    return r;
}

// Persistent kernel: 256 WGs (1/CU), 2049 phases, global barrier per phase.
// WGs [0,128): layer 0, t = k.  WGs [128,256): layer 1, t = k-1 (pipelined).
// Per WG: gates[16 rows x 32 batch] = Wcat[16 x 1024] @ v[1024 x 32] via MFMA,
// K split across 4 waves, f32 partials reduced in LDS, then cell update.
// Weight A-fragments live in registers for the entire sequence (bf16, 32 VGPR).
__global__ __launch_bounds__(NTHR, 1) void lstm_persist(
    const int*   __restrict__ tokens, const float* __restrict__ emb,
    const float* __restrict__ w_ih,   const float* __restrict__ w_hh,
    const float* __restrict__ b_ih,   const float* __restrict__ b_hh,
    const float* __restrict__ fc_w,   const float* __restrict__ fc_b,
    float* __restrict__ out,
    unsigned* __restrict__ bar, unsigned short* __restrict__ hbuf)
{
    __shared__ float part[8][16][16];   // [w*2+ct][m][c]

    const int tid   = threadIdx.x;
    const int wg    = blockIdx.x;
    const bool l1   = (wg >= NSL);
    const int s     = l1 ? (wg - NSL) : wg;
    const int layer = l1 ? 1 : 0;
    const int w     = tid >> 6;       // wave 0..3 -> K range [w*256,(w+1)*256)
    const int lane  = tid & 63;
    const int i16   = lane & 15;      // A row m / B col j / C col
    const int hi    = lane >> 4;      // k-group
    const int kb    = (w & 1) * 256;  // k offset within ih- or hh-half
    const bool xw   = (w < 2);        // wave covers k in [0,512): the "input" half

    unsigned short* const h0a_ = hbuf;
    unsigned short* const h0b_ = hbuf + NB * HID;
    unsigned short* const h1a_ = hbuf + 2 * NB * HID;
    unsigned short* const h1b_ = hbuf + 3 * NB * HID;

    // ---- A fragments (weights) once, kept in registers ----
    const int m    = i16;
    const int gg_  = m >> 2, jj_ = m & 3;
    const int rowg = gg_ * 512 + s * 4 + jj_;          // gate-major global row
    const float* wbase = xw ? (w_ih + ((size_t)layer * 2048 + rowg) * 512)
                            : (w_hh + ((size_t)layer * 2048 + rowg) * 512);
    bf16x8 A[8];
    #pragma unroll
    for (int q = 0; q < 8; ++q) {
        int koff = kb + q * 32 + hi * 8;
        float4 wa = *(const float4*)(wbase + koff);
        float4 wb = *(const float4*)(wbase + koff + 4);
        A[q] = cvt8(wa, wb);
    }

    // ---- per-thread cell state (threads 0..127 own (ejj, eb)) ----
    const int ejj = tid >> 5;     // hidden col within slice (0..3)
    const int eb  = tid & 31;     // batch
    const int ect = eb >> 4, ec = eb & 15;
    float creg = 0.0f;
    float bias[4] = {0.f, 0.f, 0.f, 0.f};
    if (tid < 128) {
        #pragma unroll
        for (int g = 0; g < 4; ++g) {
            int rg = g * 512 + s * 4 + ejj;
            bias[g] = b_ih[layer * 2048 + rg] + b_hh[layer * 2048 + rg];
        }
    }

    bool broken = false;

    for (int k = 0; k <= SEQ; ++k) {
        const int t = l1 ? (k - 1) : k;
        if (t >= 0 && t < SEQ) {
            const int p = t & 1;
            const unsigned short* h0p  = p ? h0b_ : h0a_;   // h0[t]
            const unsigned short* h0pp = p ? h0a_ : h0b_;   // h0[t-1]
            const unsigned short* h1pp = p ? h1a_ : h1b_;   // h1[t-1]

            const unsigned short* bsrc;
            if (!l1) bsrc = xw ? (const unsigned short*)nullptr : h0pp;
            else     bsrc = xw ? h0p : h1pp;

            f32x4 acc0 = {0.f, 0.f, 0.f, 0.f};
            f32x4 acc1 = {0.f, 0.f, 0.f, 0.f};

            if (bsrc == nullptr) {
                // layer-0 input half: gather embedding rows, cvt to bf16
                const int b0 = i16, b1 = 16 + i16;
                const size_t r0 = (size_t)tokens[b0 * SEQ + t] * EMBD;
                const size_t r1 = (size_t)tokens[b1 * SEQ + t] * EMBD;
                #pragma unroll
                for (int q = 0; q < 8; ++q) {
                    int koff = kb + q * 32 + hi * 8;
                    float4 xa0 = *(const float4*)(emb + r0 + koff);
                    float4 xb0 = *(const float4*)(emb + r0 + koff + 4);
                    float4 xa1 = *(const float4*)(emb + r1 + koff);
                    float4 xb1 = *(const float4*)(emb + r1 + koff + 4);
                    bf16x8 B0 = cvt8(xa0, xb0);
                    bf16x8 B1 = cvt8(xa1, xb1);
                    acc0 = __builtin_amdgcn_mfma_f32_16x16x32_bf16(A[q], B0, acc0, 0, 0, 0);
                    acc1 = __builtin_amdgcn_mfma_f32_16x16x32_bf16(A[q], B1, acc1, 0, 0, 0);
                }
            } else {
                const unsigned short* pb0 = bsrc + (size_t)i16 * HID;
                const unsigned short* pb1 = bsrc + (size_t)(16 + i16) * HID;
                #pragma unroll
                for (int q = 0; q < 8; ++q) {
                    int koff = kb + q * 32 + hi * 8;
                    bf16x8 B0 = *(const bf16x8*)(pb0 + koff);
                    bf16x8 B1 = *(const bf16x8*)(pb1 + koff);
                    acc0 = __builtin_amdgcn_mfma_f32_16x16x32_bf16(A[q], B0, acc0, 0, 0, 0);
                    acc1 = __builtin_amdgcn_mfma_f32_16x16x32_bf16(A[q], B1, acc1, 0, 0, 0);
                }
            }

            // C mapping (verified): col = lane&15, row = (lane>>4)*4 + reg
            #pragma unroll
            for (int r = 0; r < 4; ++r) {
                part[w * 2 + 0][hi * 4 + r][i16] = acc0[r];
                part[w * 2 + 1][hi * 4 + r][i16] = acc1[r];
            }
            __syncthreads();

            if (tid < 128) {
                float gate[4];
                #pragma unroll
                for (int g = 0; g < 4; ++g) {
                    int mm = g * 4 + ejj;
                    gate[g] = part[0 + ect][mm][ec] + part[2 + ect][mm][ec]
                            + part[4 + ect][mm][ec] + part[6 + ect][mm][ec] + bias[g];
                }
                // gate order: i, f, g, o
                creg = sigf(gate[1]) * creg + sigf(gate[0]) * tanhf_fast(gate[2]);
                float hv = sigf(gate[3]) * tanhf_fast(creg);
                unsigned short* hout = l1 ? (p ? h1b_ : h1a_) : (p ? h0b_ : h0a_);
                hout[eb * HID + s * 4 + ejj] = (unsigned short)f2bf(hv);
            }
        }

        // ---- device-wide barrier (monotonic counter, release/acquire, agent scope) ----
        __syncthreads();
        if (tid == 0) {
            __hip_atomic_fetch_add(bar, 1u, __ATOMIC_RELEASE, __HIP_MEMORY_SCOPE_AGENT);
            if (!broken) {
                const unsigned target = (unsigned)(k + 1) * NWG;
                int polls = 0;
                while (__hip_atomic_load(bar, __ATOMIC_ACQUIRE, __HIP_MEMORY_SCOPE_AGENT) < target) {
                    __builtin_amdgcn_s_sleep(8);
                    if (++polls > 2000000) { broken = true; break; }  // bailout: wrong answer, never hang
                }
            }
        }
        __syncthreads();
    }

    // ---- FC head: WG 0, after final barrier. h1 final = parity of t=2047 -> h1b ----
    if (wg == 0 && tid < 64) {
        const int b = tid >> 1, o = tid & 1;
        const unsigned short* hf = h1b_;
        float acc = 0.f;
        for (int j = 0; j < HID; ++j)
            acc += bf2f(hf[b * HID + j]) * fc_w[o * HID + j];
        out[b * 2 + o] = sigf(acc + fc_b[o]);
    }
}

extern "C" void kernel_launch(void* const* d_in, const int* in_sizes, int n_in,
                              void* d_out, int out_size, void* d_ws, size_t ws_size,
                              hipStream_t stream)
{
    const int*   tokens = (const int*)d_in[0];
    const float* emb    = (const float*)d_in[1];
    const float* w_ih   = (const float*)d_in[2];
    const float* w_hh   = (const float*)d_in[3];
    const float* b_ih   = (const float*)d_in[4];
    const float* b_hh   = (const float*)d_in[5];
    const float* fc_w   = (const float*)d_in[6];
    const float* fc_b   = (const float*)d_in[7];

    unsigned*       bar  = (unsigned*)d_ws;
    unsigned short* hbuf = (unsigned short*)((char*)d_ws + 4096);

    // zero barrier counter + the 4 h buffers (h[-1] = 0); c lives in registers
    hipMemsetAsync(d_ws, 0, 4096 + (size_t)4 * NB * HID * sizeof(unsigned short), stream);

    lstm_persist<<<dim3(NWG), dim3(NTHR), 0, stream>>>(
        tokens, emb, w_ih, w_hh, b_ih, b_hh, fc_w, fc_b,
        (float*)d_out, bar, hbuf);
}

// Round 3
// 26914.084 us; speedup vs baseline: 2.8819x; 1.6498x over previous
//
#include <hip/hip_runtime.h>

#define SEQ   2048
#define EMBD  512
#define HID   512
#define NB    32      // batch
#define NSL   128     // WG slices per layer (each owns 4 hidden cols x 4 gates = 16 gate rows)
#define NWG   256
#define NTHR  256
#define POLL_CAP 5000000

typedef __attribute__((ext_vector_type(8))) short bf16x8;
typedef __attribute__((ext_vector_type(4))) float f32x4;

__device__ __forceinline__ float sigf(float x) { return 1.0f / (1.0f + __expf(-x)); }
__device__ __forceinline__ float tanhf_fast(float x) {
    float e = __expf(2.0f * x);
    return (e - 1.0f) / (e + 1.0f);
}
// RNE f32 -> bf16 (bit trick; values here are tame, no NaN handling needed)
__device__ __forceinline__ short f2bf(float f) {
    unsigned u = __float_as_uint(f);
    unsigned r = (u + 0x7FFFu + ((u >> 16) & 1u)) >> 16;
    return (short)r;
}
__device__ __forceinline__ float bf2f(unsigned short s) {
    return __uint_as_float(((unsigned)s) << 16);
}
__device__ __forceinline__ bf16x8 cvt8(float4 a, float4 b) {
    bf16x8 r;
    r[0] = f2bf(a.x); r[1] = f2bf(a.y); r[2] = f2bf(a.z); r[3] = f2bf(a.w);
    r[4] = f2bf(b.x); r[5] = f2bf(b.y); r[6] = f2bf(b.z); r[7] = f2bf(b.w);
    return r;
}

// Persistent kernel: 256 WGs (1/CU), 2049 phases.
// Barrier: per-WG arrival slots (128B stride, release stores, NO RMW) +
// master sweep (relaxed loads, wave-wide vote) + single epoch flag release.
// Pollers use relaxed loads + one acquire fence on exit (no per-poll inv).
__global__ __launch_bounds__(NTHR, 1) void lstm_persist(
    const int*   __restrict__ tokens, const float* __restrict__ emb,
    const float* __restrict__ w_ih,   const float* __restrict__ w_hh,
    const float* __restrict__ b_ih,   const float* __restrict__ b_hh,
    const float* __restrict__ fc_w,   const float* __restrict__ fc_b,
    float* __restrict__ out,
    unsigned* __restrict__ epoch, unsigned* __restrict__ slots,
    unsigned short* __restrict__ hbuf)
{
    __shared__ float part[8][16][16];   // [w*2+ct][m][c]

    const int tid   = threadIdx.x;
    const int wg    = blockIdx.x;
    const bool l1   = (wg >= NSL);
    const int s     = l1 ? (wg - NSL) : wg;
    const int layer = l1 ? 1 : 0;
    const int w     = tid >> 6;       // wave 0..3 -> K range [w*256,(w+1)*256)
    const int lane  = tid & 63;
    const int i16   = lane & 15;      // A row m / B col j / C col
    const int hi    = lane >> 4;      // k-group
    const int kb    = (w & 1) * 256;  // k offset within ih- or hh-half
    const bool xw   = (w < 2);        // wave covers k in [0,512): the "input" half

    unsigned short* const h0a_ = hbuf;
    unsigned short* const h0b_ = hbuf + NB * HID;
    unsigned short* const h1a_ = hbuf + 2 * NB * HID;
    unsigned short* const h1b_ = hbuf + 3 * NB * HID;

    // ---- A fragments (weights) once, kept in registers ----
    const int m    = i16;
    const int gg_  = m >> 2, jj_ = m & 3;
    const int rowg = gg_ * 512 + s * 4 + jj_;          // gate-major global row
    const float* wbase = xw ? (w_ih + ((size_t)layer * 2048 + rowg) * 512)
                            : (w_hh + ((size_t)layer * 2048 + rowg) * 512);
    bf16x8 A[8];
    #pragma unroll
    for (int q = 0; q < 8; ++q) {
        int koff = kb + q * 32 + hi * 8;
        float4 wa = *(const float4*)(wbase + koff);
        float4 wb = *(const float4*)(wbase + koff + 4);
        A[q] = cvt8(wa, wb);
    }

    // ---- per-thread cell state (threads 0..127 own (ejj, eb)) ----
    const int ejj = tid >> 5;     // hidden col within slice (0..3)
    const int eb  = tid & 31;     // batch
    const int ect = eb >> 4, ec = eb & 31 & 15;
    float creg = 0.0f;
    float bias[4] = {0.f, 0.f, 0.f, 0.f};
    if (tid < 128) {
        #pragma unroll
        for (int g = 0; g < 4; ++g) {
            int rg = g * 512 + s * 4 + ejj;
            bias[g] = b_ih[layer * 2048 + rg] + b_hh[layer * 2048 + rg];
        }
    }

    bool broken = false;
    int polls = 0;    // cumulative across phases: a broken phase doesn't re-burn the cap

    for (int k = 0; k <= SEQ; ++k) {
        const int t = l1 ? (k - 1) : k;
        if (t >= 0 && t < SEQ) {
            const int p = t & 1;
            const unsigned short* h0p  = p ? h0b_ : h0a_;   // h0[t]
            const unsigned short* h0pp = p ? h0a_ : h0b_;   // h0[t-1]
            const unsigned short* h1pp = p ? h1a_ : h1b_;   // h1[t-1]

            const unsigned short* bsrc;
            if (!l1) bsrc = xw ? (const unsigned short*)nullptr : h0pp;
            else     bsrc = xw ? h0p : h1pp;

            f32x4 acc0 = {0.f, 0.f, 0.f, 0.f};
            f32x4 acc1 = {0.f, 0.f, 0.f, 0.f};

            if (bsrc == nullptr) {
                // layer-0 input half: gather embedding rows, cvt to bf16
                const int b0 = i16, b1 = 16 + i16;
                const size_t r0 = (size_t)tokens[b0 * SEQ + t] * EMBD;
                const size_t r1 = (size_t)tokens[b1 * SEQ + t] * EMBD;
                #pragma unroll
                for (int q = 0; q < 8; ++q) {
                    int koff = kb + q * 32 + hi * 8;
                    float4 xa0 = *(const float4*)(emb + r0 + koff);
                    float4 xb0 = *(const float4*)(emb + r0 + koff + 4);
                    float4 xa1 = *(const float4*)(emb + r1 + koff);
                    float4 xb1 = *(const float4*)(emb + r1 + koff + 4);
                    bf16x8 B0 = cvt8(xa0, xb0);
                    bf16x8 B1 = cvt8(xa1, xb1);
                    acc0 = __builtin_amdgcn_mfma_f32_16x16x32_bf16(A[q], B0, acc0, 0, 0, 0);
                    acc1 = __builtin_amdgcn_mfma_f32_16x16x32_bf16(A[q], B1, acc1, 0, 0, 0);
                }
            } else {
                const unsigned short* pb0 = bsrc + (size_t)i16 * HID;
                const unsigned short* pb1 = bsrc + (size_t)(16 + i16) * HID;
                #pragma unroll
                for (int q = 0; q < 8; ++q) {
                    int koff = kb + q * 32 + hi * 8;
                    bf16x8 B0 = *(const bf16x8*)(pb0 + koff);
                    bf16x8 B1 = *(const bf16x8*)(pb1 + koff);
                    acc0 = __builtin_amdgcn_mfma_f32_16x16x32_bf16(A[q], B0, acc0, 0, 0, 0);
                    acc1 = __builtin_amdgcn_mfma_f32_16x16x32_bf16(A[q], B1, acc1, 0, 0, 0);
                }
            }

            // C mapping (verified): col = lane&15, row = (lane>>4)*4 + reg
            #pragma unroll
            for (int r = 0; r < 4; ++r) {
                part[w * 2 + 0][hi * 4 + r][i16] = acc0[r];
                part[w * 2 + 1][hi * 4 + r][i16] = acc1[r];
            }
            __syncthreads();

            if (tid < 128) {
                float gate[4];
                #pragma unroll
                for (int g = 0; g < 4; ++g) {
                    int mm = g * 4 + ejj;
                    gate[g] = part[0 + ect][mm][ec] + part[2 + ect][mm][ec]
                            + part[4 + ect][mm][ec] + part[6 + ect][mm][ec] + bias[g];
                }
                // gate order: i, f, g, o
                creg = sigf(gate[1]) * creg + sigf(gate[0]) * tanhf_fast(gate[2]);
                float hv = sigf(gate[3]) * tanhf_fast(creg);
                unsigned short* hout = l1 ? (p ? h1b_ : h1a_) : (p ? h0b_ : h0a_);
                hout[eb * HID + s * 4 + ejj] = (unsigned short)f2bf(hv);
            }
        }

        // ---- device-wide barrier: slot arrival + master sweep + epoch flag ----
        __syncthreads();
        const unsigned target = (unsigned)(k + 1);
        if (wg == 0) {
            if (tid < 64) {
                if (tid == 0)
                    __hip_atomic_store(&slots[0], target, __ATOMIC_RELEASE, __HIP_MEMORY_SCOPE_AGENT);
                // each lane of wave 0 polls 4 slots (128B stride = 32 u32)
                for (;;) {
                    if (broken) break;
                    unsigned v0 = __hip_atomic_load(&slots[(tid +   0) * 32], __ATOMIC_RELAXED, __HIP_MEMORY_SCOPE_AGENT);
                    unsigned v1 = __hip_atomic_load(&slots[(tid +  64) * 32], __ATOMIC_RELAXED, __HIP_MEMORY_SCOPE_AGENT);
                    unsigned v2 = __hip_atomic_load(&slots[(tid + 128) * 32], __ATOMIC_RELAXED, __HIP_MEMORY_SCOPE_AGENT);
                    unsigned v3 = __hip_atomic_load(&slots[(tid + 192) * 32], __ATOMIC_RELAXED, __HIP_MEMORY_SCOPE_AGENT);
                    bool mine = (v0 >= target) & (v1 >= target) & (v2 >= target) & (v3 >= target);
                    if (__all(mine)) break;
                    __builtin_amdgcn_s_sleep(1);
                    if (++polls > POLL_CAP) broken = true;
                }
                __builtin_amdgcn_fence(__ATOMIC_ACQUIRE, "agent");
                if (tid == 0)
                    __hip_atomic_store(epoch, target, __ATOMIC_RELEASE, __HIP_MEMORY_SCOPE_AGENT);
            }
        } else {
            if (tid == 0) {
                __hip_atomic_store(&slots[wg * 32], target, __ATOMIC_RELEASE, __HIP_MEMORY_SCOPE_AGENT);
                while (!broken) {
                    unsigned e = __hip_atomic_load(epoch, __ATOMIC_RELAXED, __HIP_MEMORY_SCOPE_AGENT);
                    if (e >= target) break;
                    __builtin_amdgcn_s_sleep(4);
                    if (++polls > POLL_CAP) broken = true;
                }
                __builtin_amdgcn_fence(__ATOMIC_ACQUIRE, "agent");
            }
        }
        __syncthreads();
    }

    // ---- FC head: WG 0, after final barrier. h1 final = parity of t=2047 -> h1b ----
    if (wg == 0 && tid < 64) {
        const int b = tid >> 1, o = tid & 1;
        const unsigned short* hf = h1b_;
        float acc = 0.f;
        for (int j = 0; j < HID; ++j)
            acc += bf2f(hf[b * HID + j]) * fc_w[o * HID + j];
        out[b * 2 + o] = sigf(acc + fc_b[o]);
    }
}

extern "C" void kernel_launch(void* const* d_in, const int* in_sizes, int n_in,
                              void* d_out, int out_size, void* d_ws, size_t ws_size,
                              hipStream_t stream)
{
    const int*   tokens = (const int*)d_in[0];
    const float* emb    = (const float*)d_in[1];
    const float* w_ih   = (const float*)d_in[2];
    const float* w_hh   = (const float*)d_in[3];
    const float* b_ih   = (const float*)d_in[4];
    const float* b_hh   = (const float*)d_in[5];
    const float* fc_w   = (const float*)d_in[6];
    const float* fc_b   = (const float*)d_in[7];

    unsigned*       epoch = (unsigned*)d_ws;                        // own line
    unsigned*       slots = (unsigned*)((char*)d_ws + 256);         // slot[wg] at wg*128B
    unsigned short* hbuf  = (unsigned short*)((char*)d_ws + 65536);

    // zero epoch + slots + the 4 h buffers (h[-1] = 0); c lives in registers
    hipMemsetAsync(d_ws, 0, 65536 + (size_t)4 * NB * HID * sizeof(unsigned short), stream);

    lstm_persist<<<dim3(NWG), dim3(NTHR), 0, stream>>>(
        tokens, emb, w_ih, w_hh, b_ih, b_hh, fc_w, fc_b,
        (float*)d_out, epoch, slots, hbuf);
}

// Round 4
// 20567.004 us; speedup vs baseline: 3.7712x; 1.3086x over previous
//
#include <hip/hip_runtime.h>

#define SEQ   2048
#define EMBD  512
#define HID   512
#define NB    32      // batch
#define NSL   128     // WG slices per layer (each owns 4 hidden cols x 4 gates = 16 gate rows)
#define NWG   256
#define NTHR  256
#define POLL_CAP 5000000

typedef __attribute__((ext_vector_type(8))) short bf16x8;
typedef __attribute__((ext_vector_type(4))) float f32x4;

__device__ __forceinline__ float sigf(float x) { return 1.0f / (1.0f + __expf(-x)); }
__device__ __forceinline__ float tanhf_fast(float x) {
    float e = __expf(2.0f * x);
    return (e - 1.0f) / (e + 1.0f);
}
// RNE f32 -> bf16 (bit trick; values here are tame, no NaN handling needed)
__device__ __forceinline__ short f2bf(float f) {
    unsigned u = __float_as_uint(f);
    unsigned r = (u + 0x7FFFu + ((u >> 16) & 1u)) >> 16;
    return (short)r;
}
__device__ __forceinline__ float bf2f(unsigned short s) {
    return __uint_as_float(((unsigned)s) << 16);
}
__device__ __forceinline__ bf16x8 cvt8(float4 a, float4 b) {
    bf16x8 r;
    r[0] = f2bf(a.x); r[1] = f2bf(a.y); r[2] = f2bf(a.z); r[3] = f2bf(a.w);
    r[4] = f2bf(b.x); r[5] = f2bf(b.y); r[6] = f2bf(b.z); r[7] = f2bf(b.w);
    return r;
}

// Relaxed agent-scope atomics: proven (round 3) to read/write through to the
// LLC on gfx950 with NO fence — sweep/pollers observed remote stores inside
// the poll loop pre-fence. All cross-WG traffic uses these; zero L2 inv/wb.
__device__ __forceinline__ unsigned ld_a(const unsigned* p) {
    return __hip_atomic_load((unsigned*)p, __ATOMIC_RELAXED, __HIP_MEMORY_SCOPE_AGENT);
}
__device__ __forceinline__ void st_a(unsigned* p, unsigned v) {
    __hip_atomic_store(p, v, __ATOMIC_RELAXED, __HIP_MEMORY_SCOPE_AGENT);
}
__device__ __forceinline__ bf16x8 ld_h8(const unsigned* p) {
    union { unsigned u[4]; bf16x8 v; } x;
    x.u[0] = ld_a(p + 0); x.u[1] = ld_a(p + 1);
    x.u[2] = ld_a(p + 2); x.u[3] = ld_a(p + 3);
    return x.v;
}

// Persistent kernel: 256 WGs (1/CU), 2049 phases.
// h state: u32-packed bf16 pairs, relaxed agent atomics (LLC-coherent).
// Barrier: per-WG slot store (after __syncthreads drains vmcnt -> h at LLC),
// master wave sweeps slots, publishes epoch; pollers relaxed-poll epoch.
// No acquire/release fences anywhere -> L1/L2 stay hot across phases.
__global__ __launch_bounds__(NTHR, 1) void lstm_persist(
    const int*   __restrict__ tokens, const float* __restrict__ emb,
    const float* __restrict__ w_ih,   const float* __restrict__ w_hh,
    const float* __restrict__ b_ih,   const float* __restrict__ b_hh,
    const float* __restrict__ fc_w,   const float* __restrict__ fc_b,
    float* __restrict__ out,
    unsigned* __restrict__ epoch, unsigned* __restrict__ slots,
    unsigned* __restrict__ hbuf)
{
    __shared__ float part[8][16][16];   // [w*2+ct][m][c]

    const int tid   = threadIdx.x;
    const int wg    = blockIdx.x;
    const bool l1   = (wg >= NSL);
    const int s     = l1 ? (wg - NSL) : wg;
    const int layer = l1 ? 1 : 0;
    const int w     = tid >> 6;       // wave 0..3 -> K range [w*256,(w+1)*256)
    const int lane  = tid & 63;
    const int i16   = lane & 15;      // A row m / B col j / C col
    const int hi    = lane >> 4;      // k-group
    const int kb    = (w & 1) * 256;  // k offset within ih- or hh-half
    const bool xw   = (w < 2);        // wave covers k in [0,512): the "input" half

    // u32-packed h buffers: [b][HID/2] per buffer, 8192 u32 each
    unsigned* const h0a_ = hbuf;
    unsigned* const h0b_ = hbuf + NB * HID / 2;
    unsigned* const h1a_ = hbuf + 2 * NB * HID / 2;
    unsigned* const h1b_ = hbuf + 3 * NB * HID / 2;

    // ---- A fragments (weights) once, kept in registers ----
    const int m    = i16;
    const int gg_  = m >> 2, jj_ = m & 3;
    const int rowg = gg_ * 512 + s * 4 + jj_;          // gate-major global row
    const float* wbase = xw ? (w_ih + ((size_t)layer * 2048 + rowg) * 512)
                            : (w_hh + ((size_t)layer * 2048 + rowg) * 512);
    bf16x8 A[8];
    #pragma unroll
    for (int q = 0; q < 8; ++q) {
        int koff = kb + q * 32 + hi * 8;
        float4 wa = *(const float4*)(wbase + koff);
        float4 wb = *(const float4*)(wbase + koff + 4);
        A[q] = cvt8(wa, wb);
    }

    // ---- per-thread cell state: threads 0..63 own (pr, b); 2 hidden cols each ----
    const int eb  = tid & 31;       // batch
    const int pr  = tid >> 5;       // col-pair within slice (0..1), valid for tid<64
    const int ect = eb >> 4, ec = eb & 15;
    float cA = 0.0f, cB = 0.0f;
    float biasA[4] = {0.f,0.f,0.f,0.f}, biasB[4] = {0.f,0.f,0.f,0.f};
    if (tid < 64) {
        #pragma unroll
        for (int g = 0; g < 4; ++g) {
            int rg = g * 512 + s * 4 + pr * 2;
            biasA[g] = b_ih[layer * 2048 + rg]     + b_hh[layer * 2048 + rg];
            biasB[g] = b_ih[layer * 2048 + rg + 1] + b_hh[layer * 2048 + rg + 1];
        }
    }

    bool broken = false;
    int polls = 0;    // cumulative across phases

    for (int k = 0; k <= SEQ; ++k) {
        const int t = l1 ? (k - 1) : k;
        if (t >= 0 && t < SEQ) {
            const int p = t & 1;
            const unsigned* h0p  = p ? h0b_ : h0a_;   // h0[t]
            const unsigned* h0pp = p ? h0a_ : h0b_;   // h0[t-1]
            const unsigned* h1pp = p ? h1a_ : h1b_;   // h1[t-1]

            const unsigned* bsrc;
            if (!l1) bsrc = xw ? (const unsigned*)nullptr : h0pp;
            else     bsrc = xw ? h0p : h1pp;

            f32x4 acc0 = {0.f, 0.f, 0.f, 0.f};
            f32x4 acc1 = {0.f, 0.f, 0.f, 0.f};

            if (bsrc == nullptr) {
                // layer-0 input half: gather embedding rows, cvt to bf16
                const int b0 = i16, b1 = 16 + i16;
                const size_t r0 = (size_t)tokens[b0 * SEQ + t] * EMBD;
                const size_t r1 = (size_t)tokens[b1 * SEQ + t] * EMBD;
                #pragma unroll
                for (int q = 0; q < 8; ++q) {
                    int koff = kb + q * 32 + hi * 8;
                    float4 xa0 = *(const float4*)(emb + r0 + koff);
                    float4 xb0 = *(const float4*)(emb + r0 + koff + 4);
                    float4 xa1 = *(const float4*)(emb + r1 + koff);
                    float4 xb1 = *(const float4*)(emb + r1 + koff + 4);
                    bf16x8 B0 = cvt8(xa0, xb0);
                    bf16x8 B1 = cvt8(xa1, xb1);
                    acc0 = __builtin_amdgcn_mfma_f32_16x16x32_bf16(A[q], B0, acc0, 0, 0, 0);
                    acc1 = __builtin_amdgcn_mfma_f32_16x16x32_bf16(A[q], B1, acc1, 0, 0, 0);
                }
            } else {
                const unsigned* pb0 = bsrc + (size_t)i16 * (HID / 2);
                const unsigned* pb1 = bsrc + (size_t)(16 + i16) * (HID / 2);
                const int kb2 = kb / 2;
                #pragma unroll
                for (int q = 0; q < 8; ++q) {
                    int ko2 = kb2 + q * 16 + hi * 4;
                    bf16x8 B0 = ld_h8(pb0 + ko2);
                    bf16x8 B1 = ld_h8(pb1 + ko2);
                    acc0 = __builtin_amdgcn_mfma_f32_16x16x32_bf16(A[q], B0, acc0, 0, 0, 0);
                    acc1 = __builtin_amdgcn_mfma_f32_16x16x32_bf16(A[q], B1, acc1, 0, 0, 0);
                }
            }

            // C mapping (verified): col = lane&15, row = (lane>>4)*4 + reg
            #pragma unroll
            for (int r = 0; r < 4; ++r) {
                part[w * 2 + 0][hi * 4 + r][i16] = acc0[r];
                part[w * 2 + 1][hi * 4 + r][i16] = acc1[r];
            }
            __syncthreads();

            if (tid < 64) {
                float gA[4], gB[4];
                #pragma unroll
                for (int g = 0; g < 4; ++g) {
                    int mm = g * 4 + pr * 2;
                    gA[g] = part[0 + ect][mm][ec]     + part[2 + ect][mm][ec]
                          + part[4 + ect][mm][ec]     + part[6 + ect][mm][ec]     + biasA[g];
                    gB[g] = part[0 + ect][mm + 1][ec] + part[2 + ect][mm + 1][ec]
                          + part[4 + ect][mm + 1][ec] + part[6 + ect][mm + 1][ec] + biasB[g];
                }
                // gate order: i, f, g, o
                cA = sigf(gA[1]) * cA + sigf(gA[0]) * tanhf_fast(gA[2]);
                float hA = sigf(gA[3]) * tanhf_fast(cA);
                cB = sigf(gB[1]) * cB + sigf(gB[0]) * tanhf_fast(gB[2]);
                float hB = sigf(gB[3]) * tanhf_fast(cB);
                unsigned val = (unsigned)(unsigned short)f2bf(hA)
                             | ((unsigned)(unsigned short)f2bf(hB) << 16);
                unsigned* hout = l1 ? (p ? h1b_ : h1a_) : (p ? h0b_ : h0a_);
                st_a(hout + eb * (HID / 2) + s * 2 + pr, val);
            }
        }

        // ---- device-wide barrier, fence-free ----
        // __syncthreads drains vmcnt per wave -> our h stores are at the LLC
        // before tid0's slot store issues (in-order after s_barrier).
        __syncthreads();
        const unsigned target = (unsigned)(k + 1);
        if (wg == 0) {
            if (tid < 64) {
                if (tid == 0) st_a(&slots[0], target);
                for (;;) {
                    if (broken) break;
                    unsigned v0 = ld_a(&slots[(tid +   0) * 32]);
                    unsigned v1 = ld_a(&slots[(tid +  64) * 32]);
                    unsigned v2 = ld_a(&slots[(tid + 128) * 32]);
                    unsigned v3 = ld_a(&slots[(tid + 192) * 32]);
                    bool mine = (v0 >= target) & (v1 >= target) & (v2 >= target) & (v3 >= target);
                    if (__all(mine)) break;
                    __builtin_amdgcn_s_sleep(1);
                    if (++polls > POLL_CAP) broken = true;
                }
                if (tid == 0) st_a(epoch, target);
            }
        } else {
            if (tid == 0) {
                st_a(&slots[wg * 32], target);
                while (!broken) {
                    if (ld_a(epoch) >= target) break;
                    __builtin_amdgcn_s_sleep(2);
                    if (++polls > POLL_CAP) broken = true;
                }
            }
        }
        __syncthreads();
    }

    // ---- FC head: WG 0, after final barrier. h1 final parity -> h1b ----
    if (wg == 0 && tid < 64) {
        const int b = tid >> 1, o = tid & 1;
        float acc = 0.f;
        for (int j2 = 0; j2 < HID / 2; ++j2) {
            unsigned u = ld_a(h1b_ + b * (HID / 2) + j2);
            acc += bf2f((unsigned short)(u & 0xFFFFu)) * fc_w[o * HID + 2 * j2]
                 + bf2f((unsigned short)(u >> 16))     * fc_w[o * HID + 2 * j2 + 1];
        }
        out[b * 2 + o] = sigf(acc + fc_b[o]);
    }
}

extern "C" void kernel_launch(void* const* d_in, const int* in_sizes, int n_in,
                              void* d_out, int out_size, void* d_ws, size_t ws_size,
                              hipStream_t stream)
{
    const int*   tokens = (const int*)d_in[0];
    const float* emb    = (const float*)d_in[1];
    const float* w_ih   = (const float*)d_in[2];
    const float* w_hh   = (const float*)d_in[3];
    const float* b_ih   = (const float*)d_in[4];
    const float* b_hh   = (const float*)d_in[5];
    const float* fc_w   = (const float*)d_in[6];
    const float* fc_b   = (const float*)d_in[7];

    unsigned* epoch = (unsigned*)d_ws;                        // own line
    unsigned* slots = (unsigned*)((char*)d_ws + 256);         // slot[wg] at wg*128B
    unsigned* hbuf  = (unsigned*)((char*)d_ws + 65536);       // 4 x 8192 u32

    // zero epoch + slots + the 4 h buffers (h[-1] = 0); c lives in registers
    hipMemsetAsync(d_ws, 0, 65536 + (size_t)4 * NB * (HID / 2) * sizeof(unsigned), stream);

    lstm_persist<<<dim3(NWG), dim3(NTHR), 0, stream>>>(
        tokens, emb, w_ih, w_hh, b_ih, b_hh, fc_w, fc_b,
        (float*)d_out, epoch, slots, hbuf);
}